// Round 1
// baseline (19404.565 us; speedup 1.0000x reference)
//
#include <hip/hip_runtime.h>
#include <math.h>

// ---------------------------------------------------------------------------
// Seq2Seq LSTM (S=128,B=64,I=H=O=1024,L=2,T=64) on gfx950.
// Round 1: correctness-first split-bf16 (3x MFMA) implementation.
//   - encoder: layer0/layer1 software-pipelined, one kernel per step (129)
//   - decoder: head folded into layer0 via Wcomb = dec_wih0 @ lin_w, so each
//     step is 2 stages (L0 cell, L1 cell); y recomputed at the end from h1
//     history as one parallel GEMM.
//   - each stage kernel: 64 blocks x 512 thr (8 waves = 4 gates x 2 K-halves),
//     mfma_f32_16x16x32_bf16, operands direct from global, LDS reduce + cell.
// ---------------------------------------------------------------------------

typedef unsigned short u16;
typedef short short8 __attribute__((ext_vector_type(8)));
typedef float f32x4 __attribute__((ext_vector_type(4)));

#define MFMA_BF16 __builtin_amdgcn_mfma_f32_16x16x32_bf16

__device__ __forceinline__ u16 f2bf(float x) {
  unsigned u = __builtin_bit_cast(unsigned, x);
  unsigned r = u + 0x7fffu + ((u >> 16) & 1u);   // RNE (no NaN inputs here)
  return (u16)(r >> 16);
}
__device__ __forceinline__ float bf2f(u16 b) {
  return __builtin_bit_cast(float, ((unsigned)b) << 16);
}

// ---------------- prep kernels ----------------

// Split fp32 -> (hi,lo) bf16 pair. If trans, writes dst[c*ldd+r] (for lin_w^T).
__global__ void split_mat(const float* __restrict__ src, u16* __restrict__ dh,
                          u16* __restrict__ dl, int n, int C, int ldd, int trans) {
  int i = blockIdx.x * 256 + threadIdx.x;
  if (i >= n) return;
  float v = src[i];
  u16 hi = f2bf(v);
  u16 lo = f2bf(v - bf2f(hi));
  int r = i / C, c = i % C;
  int idx = trans ? (c * ldd + r) : (r * ldd + c);
  dh[idx] = hi; dl[idx] = lo;
}

__global__ void zero_f4(float4* __restrict__ p, int n) {
  int i = blockIdx.x * 256 + threadIdx.x;
  if (i < n) p[i] = make_float4(0.f, 0.f, 0.f, 0.f);
}

// bcomb[n] = dec_b0[n] + sum_k lin_b[k] * dec_wih0[n][k]   (one block per n)
__global__ void bias_comb(const float* __restrict__ db0, const float* __restrict__ lb,
                          const float* __restrict__ wih, float* __restrict__ out) {
  __shared__ float red[256];
  int n = blockIdx.x;
  float s = 0.f;
  for (int k = threadIdx.x; k < 1024; k += 256) s += lb[k] * wih[(size_t)n * 1024 + k];
  red[threadIdx.x] = s;
  __syncthreads();
  for (int d = 128; d > 0; d >>= 1) {
    if (threadIdx.x < d) red[threadIdx.x] += red[threadIdx.x + d];
    __syncthreads();
  }
  if (threadIdx.x == 0) out[n] = db0[n] + red[0];
}

// ---------------- generic split-bf16 GEMM: C[M,N] = A[M,K] * B[N,K]^T ------
// mode 0: write split bf16 (hi/lo) to Ch/Cl (Wcomb build)
// mode 1: write fp32 + bias to outp with row=(t*64+b) -> out[b][t][col] scatter
__global__ __launch_bounds__(256) void gemm_split(
    const u16* __restrict__ Ah, const u16* __restrict__ Al, int lda,
    const u16* __restrict__ Bh, const u16* __restrict__ Bl, int ldb,
    int K, u16* __restrict__ Ch, u16* __restrict__ Cl, int ldc,
    float* __restrict__ outp, const float* __restrict__ bias, int mode, int gn) {
  int bm = blockIdx.x / gn, bn = blockIdx.x % gn;
  int l = threadIdx.x & 63, w = threadIdx.x >> 6;
  int n0 = bn * 64 + w * 16;
  int rr = l & 15, ko = (l >> 4) << 3;
  int nrow = n0 + rr;
  f32x4 acc[4] = {};
  for (int kk = 0; kk < K; kk += 32) {
    short8 bh = *(const short8*)(Bh + (size_t)nrow * ldb + kk + ko);
    short8 bl = *(const short8*)(Bl + (size_t)nrow * ldb + kk + ko);
#pragma unroll
    for (int mt = 0; mt < 4; ++mt) {
      size_t ao = (size_t)(bm * 64 + mt * 16 + rr) * lda + kk + ko;
      short8 ah = *(const short8*)(Ah + ao);
      short8 al = *(const short8*)(Al + ao);
      acc[mt] = MFMA_BF16(ah, bh, acc[mt], 0, 0, 0);
      acc[mt] = MFMA_BF16(ah, bl, acc[mt], 0, 0, 0);
      acc[mt] = MFMA_BF16(al, bh, acc[mt], 0, 0, 0);
    }
  }
  int q = l >> 4;
#pragma unroll
  for (int mt = 0; mt < 4; ++mt)
#pragma unroll
    for (int r = 0; r < 4; ++r) {
      int row = bm * 64 + mt * 16 + q * 4 + r;
      int col = n0 + rr;
      float v = acc[mt][r];
      if (mode == 0) {
        u16 hh = f2bf(v);
        Ch[(size_t)row * ldc + col] = hh;
        Cl[(size_t)row * ldc + col] = f2bf(v - bf2f(hh));
      } else {
        int t = row >> 6, b = row & 63;
        outp[(size_t)b * 65536 + t * 1024 + col] = v + bias[col];
      }
    }
}

// ---------------- LSTM stage kernel ----------------
// gates[64,4096] = A0[64,1024]*W0^T + A1[64,1024]*W1^T + bias ; then cell.
// Block covers 16 h-columns (all 4 gates, all 64 batch rows).
// 8 waves: wave = gate(4) x K-half(2). LDS reduce, fused cell epilogue.

struct HalfOp { const u16 *Ah, *Al, *Wh, *Wl; };
struct StageArgs {
  HalfOp op0, op1;
  const float* bias;
  float* c;            // [64][1024] fp32, in-place
  u16 *Hh, *Hl;        // h out (split)
  u16 *Gh, *Gl;        // optional duplicate h dest (H1 history), may be null
  int active;
};

__global__ __launch_bounds__(512) void lstm_stage(StageArgs a0, StageArgs a1, int nper) {
  bool first = ((int)blockIdx.x < nper);
  StageArgs S = first ? a0 : a1;
  if (!S.active) return;
  int jt = first ? blockIdx.x : (blockIdx.x - nper);
  int tid = threadIdx.x;
  int l = tid & 63, w = tid >> 6;
  int g = w & 3, kc = w >> 2;
  int j0 = jt << 4;
  int rr = l & 15, ko = (l >> 4) << 3;
  HalfOp op = kc ? S.op1 : S.op0;
  const u16* __restrict__ Wh = op.Wh + (size_t)(g * 1024 + j0 + rr) * 1024;
  const u16* __restrict__ Wl = op.Wl + (size_t)(g * 1024 + j0 + rr) * 1024;
  const u16* __restrict__ Ah = op.Ah;
  const u16* __restrict__ Al = op.Al;
  f32x4 acc[4] = {};
  for (int kk = 0; kk < 1024; kk += 32) {
    short8 bh = *(const short8*)(Wh + kk + ko);
    short8 bl = *(const short8*)(Wl + kk + ko);
#pragma unroll
    for (int mt = 0; mt < 4; ++mt) {
      size_t ao = (size_t)((mt << 4) + rr) * 1024 + kk + ko;
      short8 ah = *(const short8*)(Ah + ao);
      short8 al = *(const short8*)(Al + ao);
      acc[mt] = MFMA_BF16(ah, bh, acc[mt], 0, 0, 0);
      acc[mt] = MFMA_BF16(ah, bl, acc[mt], 0, 0, 0);
      acc[mt] = MFMA_BF16(al, bh, acc[mt], 0, 0, 0);
    }
  }
  __shared__ float redu[4][64][16];
  int q = l >> 4;
  if (kc) {
#pragma unroll
    for (int mt = 0; mt < 4; ++mt)
#pragma unroll
      for (int r = 0; r < 4; ++r)
        redu[g][(mt << 4) + (q << 2) + r][rr] = acc[mt][r];
  }
  __syncthreads();
  if (!kc) {
    float bv = S.bias[g * 1024 + j0 + rr];
#pragma unroll
    for (int mt = 0; mt < 4; ++mt)
#pragma unroll
      for (int r = 0; r < 4; ++r) {
        int row = (mt << 4) + (q << 2) + r;
        redu[g][row][rr] = acc[mt][r] + redu[g][row][rr] + bv;
      }
  }
  __syncthreads();
  // cell: 64 batch x 16 cols = 1024 elements over 512 threads
  for (int e = tid; e < 1024; e += 512) {
    int b = e >> 4, jj = e & 15;
    int col = j0 + jj;
    float gi = redu[0][b][jj], gf = redu[1][b][jj];
    float gg = redu[2][b][jj], go = redu[3][b][jj];
    size_t ci = (size_t)b * 1024 + col;
    float cold = S.c[ci];
    float is = 1.f / (1.f + expf(-gi));
    float fs = 1.f / (1.f + expf(-gf));
    float gt = tanhf(gg);
    float os = 1.f / (1.f + expf(-go));
    float cn = fs * cold + is * gt;
    S.c[ci] = cn;
    float h = os * tanhf(cn);
    u16 hh = f2bf(h);
    u16 hl = f2bf(h - bf2f(hh));
    S.Hh[ci] = hh; S.Hl[ci] = hl;
    if (S.Gh) { S.Gh[ci] = hh; S.Gl[ci] = hl; }
  }
}

// ---------------- host ----------------

static inline StageArgs mkStage(const u16* a0h, const u16* a0l, const u16* w0h, const u16* w0l,
                                const u16* a1h, const u16* a1l, const u16* w1h, const u16* w1l,
                                const float* bias, float* c, u16* Hh, u16* Hl,
                                u16* Gh, u16* Gl, int act) {
  StageArgs s;
  s.op0 = {a0h, a0l, w0h, w0l};
  s.op1 = {a1h, a1l, w1h, w1l};
  s.bias = bias; s.c = c; s.Hh = Hh; s.Hl = Hl; s.Gh = Gh; s.Gl = Gl; s.active = act;
  return s;
}

extern "C" void kernel_launch(void* const* d_in, const int* in_sizes, int n_in,
                              void* d_out, int out_size, void* d_ws, size_t ws_size,
                              hipStream_t stream) {
  (void)in_sizes; (void)n_in; (void)out_size; (void)ws_size;
  const float* input_seq = (const float*)d_in[0];   // [128,64,1024]
  const float* enc_wih   = (const float*)d_in[1];   // [2,4096,1024]
  const float* enc_whh   = (const float*)d_in[2];
  const float* enc_b     = (const float*)d_in[3];   // [2,4096]
  const float* dec_wih   = (const float*)d_in[4];
  const float* dec_whh   = (const float*)d_in[5];
  const float* dec_b     = (const float*)d_in[6];
  const float* lin_w     = (const float*)d_in[7];   // [1024,1024]
  const float* lin_b     = (const float*)d_in[8];   // [1024]
  float* out = (float*)d_out;                       // [64,64,1024]

  const size_t WE = 4096ull * 1024;   // weight-matrix elements
  const size_t HB = 64ull * 1024;     // h/c slot elements
  char* ws = (char*)d_ws;
  size_t off = 0;
  auto alloc16 = [&](size_t elems) {  // u16 array
    u16* p = (u16*)(ws + off);
    off = (off + elems * 2 + 255) & ~(size_t)255;
    return p;
  };
  auto allocf = [&](size_t elems) {
    float* p = (float*)(ws + off);
    off = (off + elems * 4 + 255) & ~(size_t)255;
    return p;
  };

  // split weight pairs (hi,lo)
  u16 *WihE0h = alloc16(WE), *WihE0l = alloc16(WE);
  u16 *WhhE0h = alloc16(WE), *WhhE0l = alloc16(WE);
  u16 *WihE1h = alloc16(WE), *WihE1l = alloc16(WE);
  u16 *WhhE1h = alloc16(WE), *WhhE1l = alloc16(WE);
  u16 *WihD0h = alloc16(WE), *WihD0l = alloc16(WE);
  u16 *WhhD0h = alloc16(WE), *WhhD0l = alloc16(WE);
  u16 *WihD1h = alloc16(WE), *WihD1l = alloc16(WE);
  u16 *WhhD1h = alloc16(WE), *WhhD1l = alloc16(WE);
  u16 *Wcombh = alloc16(WE), *Wcombl = alloc16(WE);
  u16 *WLh  = alloc16(1024 * 1024), *WLl  = alloc16(1024 * 1024);   // lin_w [o][h]
  u16 *WLTh = alloc16(1024 * 1024), *WLTl = alloc16(1024 * 1024);   // lin_w^T [h][o]
  u16 *XSh = alloc16(8192ull * 1024), *XSl = alloc16(8192ull * 1024); // input split
  u16 *H1h = alloc16(64 * HB), *H1l = alloc16(64 * HB);             // decoder h1 history
  // states (contiguous, zeroed): h0[2],h1[2] split + c0,c1
  u16 *h0h = alloc16(2 * HB), *h0l = alloc16(2 * HB);
  u16 *h1h = alloc16(2 * HB), *h1l = alloc16(2 * HB);
  float *c0 = allocf(HB), *c1 = allocf(HB);
  float *bdec0 = allocf(4096);

  // 1) zero states (1.5 MB region starting at h0h)
  {
    int n4 = (int)((2 * HB * 2 * 4 /*u16 arrays*/ + 2 * HB * 4 /*c*/) / 16);
    zero_f4<<<dim3((n4 + 255) / 256), dim3(256), 0, stream>>>((float4*)h0h, n4);
  }
  // 2) split inputs & weights
  auto split = [&](const float* src, u16* dh, u16* dl, int n, int trans) {
    split_mat<<<dim3((n + 255) / 256), dim3(256), 0, stream>>>(src, dh, dl, n, 1024, 1024, trans);
  };
  split(input_seq, XSh, XSl, 8192 * 1024, 0);
  split(enc_wih,        WihE0h, WihE0l, (int)WE, 0);
  split(enc_whh,        WhhE0h, WhhE0l, (int)WE, 0);
  split(enc_wih + WE,   WihE1h, WihE1l, (int)WE, 0);
  split(enc_whh + WE,   WhhE1h, WhhE1l, (int)WE, 0);
  split(dec_wih,        WihD0h, WihD0l, (int)WE, 0);
  split(dec_whh,        WhhD0h, WhhD0l, (int)WE, 0);
  split(dec_wih + WE,   WihD1h, WihD1l, (int)WE, 0);
  split(dec_whh + WE,   WhhD1h, WhhD1l, (int)WE, 0);
  split(lin_w, WLh,  WLl,  1024 * 1024, 0);
  split(lin_w, WLTh, WLTl, 1024 * 1024, 1);
  // 3) combined decoder-L0 bias
  bias_comb<<<dim3(4096), dim3(256), 0, stream>>>(dec_b, lin_b, dec_wih, bdec0);
  // 4) Wcomb[n][h] = sum_j dec_wih0[n][j] * lin_w[j][h]  (M=4096,N=1024,K=1024)
  gemm_split<<<dim3(64 * 16), dim3(256), 0, stream>>>(
      WihD0h, WihD0l, 1024, WLTh, WLTl, 1024, 1024,
      Wcombh, Wcombl, 1024, nullptr, nullptr, 0, 16);

  // 5) encoder: pipelined layer0(t=s) + layer1(t=s-1), s = 0..128
  for (int s = 0; s <= 128; ++s) {
    int u = s - 1;
    StageArgs L0 = mkStage(
        XSh + (size_t)s * HB, XSl + (size_t)s * HB, WihE0h, WihE0l,
        h0h + ((s + 1) & 1) * HB, h0l + ((s + 1) & 1) * HB, WhhE0h, WhhE0l,
        enc_b, c0, h0h + (s & 1) * HB, h0l + (s & 1) * HB,
        nullptr, nullptr, s < 128 ? 1 : 0);
    StageArgs L1 = mkStage(
        h0h + (u & 1) * HB, h0l + (u & 1) * HB, WihE1h, WihE1l,
        h1h + ((u + 1) & 1) * HB, h1l + ((u + 1) & 1) * HB, WhhE1h, WhhE1l,
        enc_b + 4096, c1, h1h + (u & 1) * HB, h1l + (u & 1) * HB,
        nullptr, nullptr, s >= 1 ? 1 : 0);
    lstm_stage<<<dim3(128), dim3(512), 0, stream>>>(L0, L1, 64);
  }

  // 6) decoder: per step, stage A (layer0, head folded) then stage B (layer1)
  for (int t = 0; t < 64; ++t) {
    StageArgs A;
    if (t == 0) {
      A = mkStage(XSh + 127ull * HB, XSl + 127ull * HB, WihD0h, WihD0l,
                  h0h + ((t + 1) & 1) * HB, h0l + ((t + 1) & 1) * HB, WhhD0h, WhhD0l,
                  dec_b, c0, h0h + (t & 1) * HB, h0l + (t & 1) * HB,
                  nullptr, nullptr, 1);
    } else {
      A = mkStage(h1h + ((t - 1) & 1) * HB, h1l + ((t - 1) & 1) * HB, Wcombh, Wcombl,
                  h0h + ((t + 1) & 1) * HB, h0l + ((t + 1) & 1) * HB, WhhD0h, WhhD0l,
                  bdec0, c0, h0h + (t & 1) * HB, h0l + (t & 1) * HB,
                  nullptr, nullptr, 1);
    }
    lstm_stage<<<dim3(64), dim3(512), 0, stream>>>(A, A, 64);
    StageArgs Bst = mkStage(
        h0h + (t & 1) * HB, h0l + (t & 1) * HB, WihD1h, WihD1l,
        h1h + ((t + 1) & 1) * HB, h1l + ((t + 1) & 1) * HB, WhhD1h, WhhD1l,
        dec_b + 4096, c1, h1h + (t & 1) * HB, h1l + (t & 1) * HB,
        H1h + (size_t)t * HB, H1l + (size_t)t * HB, 1);
    lstm_stage<<<dim3(64), dim3(512), 0, stream>>>(Bst, Bst, 64);
  }

  // 7) y[b][t][o] = H1[t*64+b][:] . lin_w[o][:] + lin_b[o]
  gemm_split<<<dim3(64 * 16), dim3(256), 0, stream>>>(
      H1h, H1l, 1024, WLh, WLl, 1024, 1024,
      nullptr, nullptr, 0, out, lin_b, 1, 16);
}